// Round 1
// baseline (598.271 us; speedup 1.0000x reference)
//
#include <hip/hip_runtime.h>
#include <cstdint>
#include <cstddef>

#define NEG_SLOPE 0.2f
#define GROWS 32

// ---------------------------------------------------------------------------
// GEMM: feat[n][128] = X[n][128] @ W[128][128], fused el/er head reductions.
// One block = 128 threads (2 waves). Thread t owns output column t and keeps
// W[:,t] in 128 VGPRs. X-row loads are wave-uniform -> scalar loads.
// ---------------------------------------------------------------------------
__global__ __launch_bounds__(128) void gemm_attn_kernel(
    const float* __restrict__ X, const float* __restrict__ W,
    const float* __restrict__ al, const float* __restrict__ ar,
    float* __restrict__ feat, float* __restrict__ el, float* __restrict__ er,
    int n)
{
    const int t = threadIdx.x;          // 0..127 = output column = h*32+d
    const int lane = t & 63;

    float wcol[128];
#pragma unroll
    for (int k = 0; k < 128; ++k) wcol[k] = W[k * 128 + t];

    const float alv = al[t];
    const float arv = ar[t];

    int r0 = blockIdx.x * GROWS;
    int r1 = r0 + GROWS; if (r1 > n) r1 = n;

    for (int r = r0; r < r1; ++r) {
        const float* __restrict__ xr = X + (size_t)r * 128;
        float acc = 0.f;
#pragma unroll
        for (int k4 = 0; k4 < 32; ++k4) {
            const float4 xv = ((const float4*)xr)[k4];
            acc += xv.x * wcol[4 * k4 + 0];
            acc += xv.y * wcol[4 * k4 + 1];
            acc += xv.z * wcol[4 * k4 + 2];
            acc += xv.w * wcol[4 * k4 + 3];
        }
        feat[(size_t)r * 128 + t] = acc;

        // el[r][h] = sum_d feat[r][h][d]*al[h][d]  (reduce over 32 lanes)
        float pl = acc * alv;
        float pr = acc * arv;
#pragma unroll
        for (int m = 16; m >= 1; m >>= 1) {
            pl += __shfl_xor(pl, m);
            pr += __shfl_xor(pr, m);
        }
        if ((lane & 31) == 0) {
            const int head = t >> 5;            // 0..3
            el[(size_t)r * 4 + head] = pl;
            er[(size_t)r * 4 + head] = pr;
        }
    }
}

// ---------------------------------------------------------------------------
// CSR build: degree count -> single-block scan -> scatter
// ---------------------------------------------------------------------------
__global__ void degree_kernel(const int* __restrict__ dst, int* __restrict__ deg, int E)
{
    int e = blockIdx.x * blockDim.x + threadIdx.x;
    if (e < E) atomicAdd(&deg[dst[e]], 1);
}

__global__ __launch_bounds__(1024) void scan_kernel(
    const int* __restrict__ deg, int* __restrict__ off, int n)
{
    __shared__ int wsums[16];
    __shared__ int s_carry;
    const int tid  = threadIdx.x;       // 0..1023
    const int lane = tid & 63;
    const int wid  = tid >> 6;          // 0..15

    if (tid == 0) { s_carry = 0; off[0] = 0; }
    __syncthreads();

    for (int base = 0; base < n; base += 1024) {
        const int i = base + tid;
        int v = (i < n) ? deg[i] : 0;

        // inclusive wave scan
        int x = v;
#pragma unroll
        for (int d = 1; d < 64; d <<= 1) {
            int y = __shfl_up(x, d);
            if (lane >= d) x += y;
        }
        if (lane == 63) wsums[wid] = x;
        __syncthreads();

        if (wid == 0 && lane < 16) {
            int xx = wsums[lane];
#pragma unroll
            for (int d = 1; d < 16; d <<= 1) {
                int y = __shfl_up(xx, d);
                if (lane >= d) xx += y;
            }
            wsums[lane] = xx;           // inclusive scan of wave sums
        }
        __syncthreads();

        const int waveprefix = (wid == 0) ? 0 : wsums[wid - 1];
        const int incl = s_carry + waveprefix + x;
        if (i < n) off[i + 1] = incl;
        __syncthreads();
        if (tid == 0) s_carry += wsums[15];
        __syncthreads();
    }
}

__global__ void scatter_kernel(const int* __restrict__ src, const int* __restrict__ dst,
                               const int* __restrict__ off, int* __restrict__ cursor,
                               int* __restrict__ csr_src, int E)
{
    int e = blockIdx.x * blockDim.x + threadIdx.x;
    if (e < E) {
        const int d = dst[e];
        const int pos = off[d] + atomicAdd(&cursor[d], 1);
        csr_src[pos] = src[e];
    }
}

// ---------------------------------------------------------------------------
// Aggregation: one 64-lane wave per destination node.
// Lane holds flattened dims f0=lane (heads 0/1) and f1=lane+64 (heads 2/3).
// Softmax weights computed inline from el/er (no max-subtraction; |e| small).
// ---------------------------------------------------------------------------
template <bool LAYER2>
__global__ __launch_bounds__(256) void agg_kernel(
    const int* __restrict__ off, const int* __restrict__ csr_src,
    const float* __restrict__ feat, const float* __restrict__ el,
    const float* __restrict__ er, const float* __restrict__ resid,
    const float* __restrict__ bias, float* __restrict__ out, int n)
{
    const int lane = threadIdx.x & 63;
    const int node = blockIdx.x * 4 + (threadIdx.x >> 6);
    if (node >= n) return;

    const int ha = lane >> 5;           // head of f0: 0 or 1 (f1 head = ha+2)
    const int f0 = lane, f1 = lane + 64;

    const float er_a = er[(size_t)node * 4 + ha];
    const float er_b = er[(size_t)node * 4 + ha + 2];

    const int beg = off[node], end = off[node + 1];

    float acc0 = 0.f, acc1 = 0.f, swa = 0.f, swb = 0.f;
    for (int j = beg; j < end; ++j) {
        const int s = csr_src[j];                       // wave-uniform
        float ea = el[(size_t)s * 4 + ha] + er_a;
        float eb = el[(size_t)s * 4 + ha + 2] + er_b;
        ea = (ea >= 0.f) ? ea : NEG_SLOPE * ea;         // leaky_relu
        eb = (eb >= 0.f) ? eb : NEG_SLOPE * eb;
        const float wa = __expf(ea);
        const float wb = __expf(eb);
        const float* __restrict__ fs = feat + (size_t)s * 128;
        acc0 += wa * fs[f0];
        acc1 += wb * fs[f1];
        swa += wa; swb += wb;
    }

    const float r0 = acc0 / fmaxf(swa, 1e-9f);
    const float r1 = acc1 / fmaxf(swb, 1e-9f);

    float v0 = r0 + resid[(size_t)node * 128 + f0] + bias[f0];
    float v1 = r1 + resid[(size_t)node * 128 + f1] + bias[f1];

    if (!LAYER2) {
        v0 = (v0 > 0.f) ? v0 : expm1f(v0);              // elu
        v1 = (v1 > 0.f) ? v1 : expm1f(v1);
        out[(size_t)node * 128 + f0] = v0;
        out[(size_t)node * 128 + f1] = v1;
    } else {
        float s2 = v0 + v1;                 // heads {ha, ha+2} for dim lane&31
        s2 += __shfl_xor(s2, 32);           // + heads {1-ha?, ...} = all 4
        if (lane < 32) out[(size_t)node * 32 + lane] = s2 * 0.25f;
    }
}

// ---------------------------------------------------------------------------
extern "C" void kernel_launch(void* const* d_in, const int* in_sizes, int n_in,
                              void* d_out, int out_size, void* d_ws, size_t ws_size,
                              hipStream_t stream)
{
    const float* x   = (const float*)d_in[0];
    const float* W1  = (const float*)d_in[1];
    const float* al1 = (const float*)d_in[2];
    const float* ar1 = (const float*)d_in[3];
    const float* b1  = (const float*)d_in[4];
    const float* W2  = (const float*)d_in[5];
    const float* al2 = (const float*)d_in[6];
    const float* ar2 = (const float*)d_in[7];
    const float* b2  = (const float*)d_in[8];
    const int*   src = (const int*)d_in[9];
    const int*   dst = (const int*)d_in[10];

    const int n = in_sizes[0] / 128;
    const int E = in_sizes[9];
    float* out = (float*)d_out;

    char* p = (char*)d_ws;
    float* feat = (float*)p; p += (size_t)n * 128 * sizeof(float);
    float* h1   = (float*)p; p += (size_t)n * 128 * sizeof(float);
    float* el   = (float*)p; p += (size_t)n * 4 * sizeof(float);
    float* er   = (float*)p; p += (size_t)n * 4 * sizeof(float);
    int* off    = (int*)p;   p += (size_t)(n + 1) * sizeof(int);
    int* deg    = (int*)p;   p += (size_t)n * sizeof(int);
    int* cursor = (int*)p;   p += (size_t)n * sizeof(int);
    int* csr    = (int*)p;   p += (size_t)E * sizeof(int);

    // zero deg + cursor (contiguous); everything else fully overwritten
    hipMemsetAsync(deg, 0, (size_t)(2 * n + 1) * sizeof(int), stream);

    const int gemm_grid = (n + GROWS - 1) / GROWS;
    const int edge_grid = (E + 255) / 256;
    const int agg_grid  = (n + 3) / 4;

    // layer 1 dense + attn coefficients
    gemm_attn_kernel<<<gemm_grid, 128, 0, stream>>>(x, W1, al1, ar1, feat, el, er, n);
    // CSR build (graph shared by both layers)
    degree_kernel<<<edge_grid, 256, 0, stream>>>(dst, deg, E);
    scan_kernel<<<1, 1024, 0, stream>>>(deg, off, n);
    scatter_kernel<<<edge_grid, 256, 0, stream>>>(src, dst, off, cursor, csr, E);
    // layer 1 aggregation (+residual +bias +elu) -> h1
    agg_kernel<false><<<agg_grid, 256, 0, stream>>>(off, csr, feat, el, er, x, b1, h1, n);
    // layer 2 dense + attn coefficients (feat buffer reused)
    gemm_attn_kernel<<<gemm_grid, 128, 0, stream>>>(h1, W2, al2, ar2, feat, el, er, n);
    // layer 2 aggregation (+residual +bias, head-mean) -> out
    agg_kernel<true><<<agg_grid, 256, 0, stream>>>(off, csr, feat, el, er, h1, b2, out, n);
}